// Round 5
// baseline (2832.397 us; speedup 1.0000x reference)
//
#include <hip/hip_runtime.h>
#include <math.h>

// NestedOscillator — 2-wave producer/consumer pass1 + parallel replay pass2.
//
// Single-wave issue model (fit to R2/R3/R4: ~4.4 cyc per VALU instr): minimize
// VALU per step; SALU work co-issues free. Slow chain (wave 0) and fast chain
// (wave 1) are coupled only via crossed-flags (function of slow alone), so they
// run CONCURRENTLY; flags flow through a 4-slot LDS ring, one __syncthreads per
// 25-step batch. Ring safety: slot b&3 written at iter b, read at iter b+1,
// rewritten at iter b+4 — producer can't reach iter b+4 until consumer passed
// barrier b+2 (after its read). One barrier per batch.
//
// Bitwise-exactness (absmax must be 0; validated machinery from R1-R4):
//  - np.mod(x,2pi), x in [0,4pi): conditional +/-2pi is Sterbenz-exact.
//  - threshold trick (R4-validated): fl(x+d)>=2pi <=> x>=T, T by exact ulp-walk.
//  - x + 0.0f == x bitwise for x>=+0.
//  - crossed(t) == slow-wrap at step t-1 (proof in R2 header).
//  - fast fused step (k==0.5 only): fma(tf, m, namt), m in {1,k},
//    namt in {0,-2pi,-2pi*k}: all four cases exact (Sterbenz sub, *0.5 exact,
//    tf*0.5-pi Sterbenz-exact == (tf-2pi)*0.5). Generic k: sub+mul (R3 form).
//  - reset product nf*k < 2pi -> reference's outer mod is identity.
//  - omega = (float)exp((double)log_omega) == numpy f32 exp (R1-R4).

#define TWO_PI_F 6.28318530717958647692f
#define K_STEPS  25

// Exact min x with fl(x+d) >= TWO_PI_F (monotone predicate -> ulp-walk exact).
__device__ __forceinline__ float wrap_threshold(float d)
{
    float x = TWO_PI_F - d;
    for (int i = 0; i < 256 && (x + d >= TWO_PI_F); ++i)
        x = __uint_as_float(__float_as_uint(x) - 1u);
    for (int i = 0; i < 256 && (x + d < TWO_PI_F); ++i)
        x = __uint_as_float(__float_as_uint(x) + 1u);
    return x;
}

template <bool FUSED>
__device__ __forceinline__ void scan_core(
    int wave, int lane, float ds, float df, float k, float Ts, float Tf,
    float* __restrict__ snapS, float* __restrict__ snapF,
    unsigned* __restrict__ flags, unsigned* ring, int nchunk)
{
    const float nsel_cross = -(TWO_PI_F * k);   // exact when k==0.5 (== -pi)
    float slow = 0.0f, fast = 0.0f;
    unsigned prevword = 0;

    for (int b = 0; b <= nchunk; ++b) {
        // ---- producer: slow chain, batch b (3 VALU/step + SALU) ----
        if (wave == 0 && b < nchunk && lane == 0) {
            snapS[b] = slow;
            unsigned fl = 0;
#pragma unroll
            for (int i = 0; i < K_STEPS; ++i) {
                const unsigned wb = (unsigned)__ballot(slow >= Ts) & 1u; // scalar
                fl |= wb << i;                                  // SALU
                const float namt = wb ? -TWO_PI_F : 0.0f;       // s_cselect
                slow = (slow + ds) + namt;                      // 2 v_add chain
            }
            ring[b & 3] = fl;
            flags[b] = fl;
        }
        __syncthreads();
        // ---- consumer: fast chain, batch b-1 (4-5 VALU/step + SALU) ----
        if (wave == 1 && b >= 1) {
            const int c = b - 1;
            const unsigned cur = ring[c & 3];   // uniform LDS broadcast
            if (lane == 0) {
                snapF[c] = fast;
#pragma unroll
                for (int i = 0; i < K_STEPS; ++i) {
                    const unsigned cr = (i == 0)
                        ? ((prevword >> (K_STEPS - 1)) & 1u)
                        : ((cur >> (i - 1)) & 1u);              // SALU
                    const float tf = fast + df;
                    if (FUSED) {
                        const float m    = cr ? k : 1.0f;               // s_cselect
                        const float nsel = cr ? nsel_cross : -TWO_PI_F; // s_cselect
                        const float namt = (fast >= Tf) ? nsel : 0.0f;  // cmp+cndmask
                        fast = fmaf(tf, m, namt);                       // v_fma
                    } else {
                        const float m   = cr ? k : 1.0f;
                        const float amt = (fast >= Tf) ? TWO_PI_F : 0.0f;
                        fast = (tf - amt) * m;                  // sub+mul (R3 form)
                    }
                }
            }
            prevword = cur;
        }
    }
}

__global__ __launch_bounds__(128, 1)
void osc_pass1(const float* __restrict__ lsw, const float* __restrict__ lfw,
               const float* __restrict__ rs,
               float* __restrict__ snapS, float* __restrict__ snapF,
               unsigned* __restrict__ flags, int nchunk)
{
    __shared__ unsigned ring[4];
    const int wave = threadIdx.x >> 6;
    const int lane = threadIdx.x & 63;

    const float ws = (float)exp((double)lsw[0]);
    const float wf = (float)exp((double)lfw[0]);
    const float k  = 1.0f - rs[0];
    const float ds = ws * 0.001f;
    const float df = wf * 0.001f;
    const float Ts = wrap_threshold(ds);
    const float Tf = wrap_threshold(df);

    if (k == 0.5f)   // uniform across block -> barrier-legal
        scan_core<true >(wave, lane, ds, df, k, Ts, Tf, snapS, snapF, flags, ring, nchunk);
    else
        scan_core<false>(wave, lane, ds, df, k, Ts, Tf, snapS, snapF, flags, ring, nchunk);
}

__global__ __launch_bounds__(256)
void osc_pass2(const float* __restrict__ lsw, const float* __restrict__ lfw,
               const float* __restrict__ rs,
               const float* __restrict__ snapS, const float* __restrict__ snapF,
               const unsigned* __restrict__ flags,
               float* __restrict__ out, int steps, int nchunk)
{
    const int c = blockIdx.x * blockDim.x + threadIdx.x;
    if (c >= nchunk) return;

    const float ws = (float)exp((double)lsw[0]);
    const float wfq = (float)exp((double)lfw[0]);
    const float k  = 1.0f - rs[0];
    const float ds = ws * 0.001f;
    const float df = wfq * 0.001f;
    const float Ts = wrap_threshold(ds);
    const float Tf = wrap_threshold(df);
    const float inv2pi = 0.15915494309189533577f;

    float slow = snapS[c], fast = snapF[c];
    const unsigned fc = flags[c];
    const unsigned fp = (c > 0) ? flags[c - 1] : 0u;
    // bit i of w == crossed at step c*25+i
    const unsigned w = (fc << 1) | (fp >> (K_STEPS - 1));

    float* __restrict__ o_slow = out;
    float* __restrict__ o_fast = out + steps;
    float* __restrict__ o_fis  = out + 2 * steps;
    const int base = c * K_STEPS;

#pragma unroll 5
    for (int i = 0; i < K_STEPS; ++i) {
        const int t = base + i;
        if (t < steps) {
            o_slow[t] = slow;
            o_fast[t] = fast;
            o_fis[t]  = slow * inv2pi;
        }
        const float m = ((w >> i) & 1u) ? k : 1.0f;
        const float amt_s = (slow >= Ts) ? TWO_PI_F : 0.0f;
        const float amt_f = (fast >= Tf) ? TWO_PI_F : 0.0f;
        slow = (slow + ds) - amt_s;
        fast = ((fast + df) - amt_f) * m;   // *1.0f bit-exact
    }
}

extern "C" void kernel_launch(void* const* d_in, const int* in_sizes, int n_in,
                              void* d_out, int out_size, void* d_ws, size_t ws_size,
                              hipStream_t stream)
{
    const float* lsw = (const float*)d_in[0];
    const float* lfw = (const float*)d_in[1];
    const float* rs  = (const float*)d_in[2];
    float* out = (float*)d_out;
    const int steps  = out_size / 3;                     // 100000
    const int nchunk = (steps + K_STEPS - 1) / K_STEPS;  // 4000

    // workspace layout: snapS | snapF | flags  (3 * 16 KB = 48 KB)
    float*    snapS = (float*)d_ws;
    float*    snapF = snapS + nchunk;
    unsigned* flags = (unsigned*)(snapF + nchunk);

    hipLaunchKernelGGL(osc_pass1, dim3(1), dim3(128), 0, stream,
                       lsw, lfw, rs, snapS, snapF, flags, nchunk);
    const int threads = 256;
    const int blocks = (nchunk + threads - 1) / threads;
    hipLaunchKernelGGL(osc_pass2, dim3(blocks), dim3(threads), 0, stream,
                       lsw, lfw, rs, snapS, snapF, flags, out, steps, nchunk);
}